// Round 2
// baseline (1936.566 us; speedup 1.0000x reference)
//
#include <hip/hip_runtime.h>
#include <hip/hip_bf16.h>

typedef __bf16 bf16;
typedef __attribute__((ext_vector_type(4))) __bf16 bf16x4;
typedef __attribute__((ext_vector_type(8))) __bf16 bf16x8;
typedef __attribute__((ext_vector_type(4))) float f32x4;
typedef __attribute__((ext_vector_type(16))) float f32x16;

// Async global->LDS, 16B/lane. LDS dst must be wave-uniform base; lane i lands at base + i*16.
__device__ __forceinline__ void async_load16(const bf16* g, const bf16* l) {
    __builtin_amdgcn_global_load_lds(
        (const __attribute__((address_space(1))) unsigned int*)g,
        (__attribute__((address_space(3))) unsigned int*)l,
        16, 0, 0);
}

// fp32 -> bf16, 8 elems/thread, exact-cover grid.
__global__ void cvt_bf16_kernel(const float* __restrict__ in, bf16* __restrict__ out) {
    const int i = blockIdx.x * blockDim.x + threadIdx.x;
    const f32x4* p = (const f32x4*)in + (size_t)i * 2;
    f32x4 a = p[0], b = p[1];
    bf16x8 o;
    o[0] = (bf16)a[0]; o[1] = (bf16)a[1]; o[2] = (bf16)a[2]; o[3] = (bf16)a[3];
    o[4] = (bf16)b[0]; o[5] = (bf16)b[1]; o[6] = (bf16)b[2]; o[7] = (bf16)b[3];
    *((bf16x8*)out + (size_t)i) = o;
}

// C = A(bf16) @ Weff^T, Weff = W .* (SU@SV), all W/SU/SV fp32.
// NMAT==2: two weight sets (gate, up), OUT(bf16) = silu(C0) * C1.
// NMAT==1: OUT(fp32) = C0.
// A: [M][KDIM] bf16. W: [N][KDIM] f32. SU: [N][4] f32. SV: [4][KDIM] f32.
// Block = 256 thr = 4 waves; wave owns RPW x 32 of the tile. BN = 32 per matrix.
template<int BM, int KDIM, int NMAT>
__global__ __launch_bounds__(256, 2)
void mlp_gemm(const bf16* __restrict__ A,
              const float* __restrict__ W0, const float* __restrict__ SU0, const float* __restrict__ SV0,
              const float* __restrict__ W1, const float* __restrict__ SU1, const float* __restrict__ SV1,
              void* __restrict__ OUTp, const int NT)
{
    constexpr int BK  = 32;
    constexpr int BN  = 32;
    constexpr int RPW = BM / 4;        // rows per wave
    constexpr int MI  = RPW / 32;      // 32x32 m-subtiles per wave
    constexpr int NLD = RPW / 16;      // async 16B-insts per thread for A tile
    constexpr int SBS = BK + 8;        // padded sB stride (80 B, 16B-aligned)
    constexpr int KIT = KDIM / BK;

    __shared__ bf16 sA[BM * BK];               // unpadded: global_load_lds target
    __shared__ bf16 sB[NMAT][BN * SBS];

    const int tid  = threadIdx.x;
    const int lane = tid & 63;
    const int wv   = tid >> 6;
    const int m0   = blockIdx.x * BM;          // m fastest -> W-tile reuse across m-blocks
    const int n0   = blockIdx.y * BN;

    // A staging: lane l -> row (l>>2), 8-elem seg (l&3)
    const bf16* gA = A + (size_t)(m0 + wv * RPW + (lane >> 2)) * KDIM + (lane & 3) * 8;

    // W staging: 32 rows x 8 segs x 4 fp32
    const int brow = tid >> 3;
    const int bseg = tid & 7;
    const float* gW0  = W0 + (size_t)(n0 + brow) * KDIM + bseg * 4;
    const float* gSV0 = SV0 + bseg * 4;
    const f32x4  su0  = *(const f32x4*)(SU0 + (size_t)(n0 + brow) * 4);
    const float* gW1  = nullptr; const float* gSV1 = nullptr; f32x4 su1{};
    if constexpr (NMAT == 2) {
        gW1  = W1 + (size_t)(n0 + brow) * KDIM + bseg * 4;
        gSV1 = SV1 + bseg * 4;
        su1  = *(const f32x4*)(SU1 + (size_t)(n0 + brow) * 4);
    }
    bf16* sBp0 = &sB[0][brow * SBS + bseg * 4];
    bf16* sBp1 = (NMAT == 2) ? &sB[NMAT - 1][brow * SBS + bseg * 4] : nullptr;

    f32x16 acc[NMAT][MI];
#pragma unroll
    for (int mt = 0; mt < NMAT; ++mt)
#pragma unroll
        for (int mi = 0; mi < MI; ++mi)
#pragma unroll
            for (int r = 0; r < 16; ++r)
                acc[mt][mi][r] = 0.0f;

    for (int kt = 0; kt < KIT; ++kt) {
        const int k0 = kt * BK;

        // A tile: async direct-to-LDS, row-major [BM][BK]
#pragma unroll
        for (int i = 0; i < NLD; ++i)
            async_load16(gA + (size_t)i * 16 * KDIM + k0,
                         &sA[(wv * RPW + i * 16) * BK]);

        // Weight tile(s): fp32 load, rank-4 scale, cvt to bf16, padded LDS
        {
            f32x4 w  = *(const f32x4*)(gW0 + k0);
            f32x4 s0 = *(const f32x4*)(gSV0 + k0);
            f32x4 s1 = *(const f32x4*)(gSV0 + (size_t)KDIM + k0);
            f32x4 s2 = *(const f32x4*)(gSV0 + (size_t)2 * KDIM + k0);
            f32x4 s3 = *(const f32x4*)(gSV0 + (size_t)3 * KDIM + k0);
            bf16x4 ov;
#pragma unroll
            for (int j = 0; j < 4; ++j) {
                float sc = su0[0] * s0[j] + su0[1] * s1[j] + su0[2] * s2[j] + su0[3] * s3[j];
                ov[j] = (bf16)(w[j] * sc);
            }
            *(bf16x4*)sBp0 = ov;
        }
        if constexpr (NMAT == 2) {
            f32x4 w  = *(const f32x4*)(gW1 + k0);
            f32x4 s0 = *(const f32x4*)(gSV1 + k0);
            f32x4 s1 = *(const f32x4*)(gSV1 + (size_t)KDIM + k0);
            f32x4 s2 = *(const f32x4*)(gSV1 + (size_t)2 * KDIM + k0);
            f32x4 s3 = *(const f32x4*)(gSV1 + (size_t)3 * KDIM + k0);
            bf16x4 ov;
#pragma unroll
            for (int j = 0; j < 4; ++j) {
                float sc = su1[0] * s0[j] + su1[1] * s1[j] + su1[2] * s2[j] + su1[3] * s3[j];
                ov[j] = (bf16)(w[j] * sc);
            }
            *(bf16x4*)sBp1 = ov;
        }

        __syncthreads();

        // MFMA 32x32x16 bf16. A/B frag: [idx=lane&31][k=(lane>>5)*8+j].
#pragma unroll
        for (int t = 0; t < BK / 16; ++t) {
            bf16x8 af[MI];
#pragma unroll
            for (int mi = 0; mi < MI; ++mi)
                af[mi] = *(const bf16x8*)(&sA[(wv * RPW + mi * 32 + (lane & 31)) * BK
                                              + t * 16 + (lane >> 5) * 8]);
#pragma unroll
            for (int mt = 0; mt < NMAT; ++mt) {
                bf16x8 bv = *(const bf16x8*)(&sB[mt][(lane & 31) * SBS
                                                     + t * 16 + (lane >> 5) * 8]);
#pragma unroll
                for (int mi = 0; mi < MI; ++mi)
                    acc[mt][mi] = __builtin_amdgcn_mfma_f32_32x32x16_bf16(
                        af[mi], bv, acc[mt][mi], 0, 0, 0);
            }
        }
        __syncthreads();
    }

    // Epilogue. C/D: col=lane&31, row=(r&3)+8*(r>>2)+4*(lane>>5)  [m74/m101]
    const int cb = lane & 31;
    const int rq = (lane >> 5) * 4;
#pragma unroll
    for (int mi = 0; mi < MI; ++mi)
#pragma unroll
        for (int r = 0; r < 16; ++r) {
            const int row = m0 + wv * RPW + mi * 32 + rq + (r & 3) + ((r >> 2) << 3);
            const size_t idx = (size_t)row * NT + (n0 + cb);
            if constexpr (NMAT == 2) {
                const float g = acc[0][mi][r];
                const float u = acc[1][mi][r];
                const float d = g / (1.0f + __expf(-g)) * u;   // silu(g)*u
                ((bf16*)OUTp)[idx] = (bf16)d;
            } else {
                ((float*)OUTp)[idx] = acc[0][mi][r];
            }
        }
}

extern "C" void kernel_launch(void* const* d_in, const int* in_sizes, int n_in,
                              void* d_out, int out_size, void* d_ws, size_t ws_size,
                              hipStream_t stream) {
    (void)in_sizes; (void)n_in; (void)out_size; (void)ws_size;

    const float* x   = (const float*)d_in[0];
    const float* gw  = (const float*)d_in[1];
    const float* gsu = (const float*)d_in[2];
    const float* gsv = (const float*)d_in[3];
    const float* uw  = (const float*)d_in[4];
    const float* usu = (const float*)d_in[5];
    const float* usv = (const float*)d_in[6];
    const float* dw  = (const float*)d_in[7];
    const float* dsu = (const float*)d_in[8];
    const float* dsv = (const float*)d_in[9];

    bf16* x_bf = (bf16*)d_ws;                              // [1024][4096]  (8 MB)
    bf16* d_sw = (bf16*)((char*)d_ws + (size_t)1024 * 4096 * 2);  // [1024][14336] (28 MB)
    float* out = (float*)d_out;                            // [1024][4096] fp32

    // K0: x -> bf16  (4.19M elems, 8/thread)
    cvt_bf16_kernel<<<2048, 256, 0, stream>>>(x, x_bf);

    // K1: fused gate+up+swiglu -> d_sw (bf16). m fastest for W-tile L2/L3 reuse.
    mlp_gemm<512, 4096, 2><<<dim3(2, 448), 256, 0, stream>>>(
        x_bf, gw, gsu, gsv, uw, usu, usv, d_sw, 14336);

    // K2: down -> out (fp32)
    mlp_gemm<512, 14336, 1><<<dim3(2, 128), 256, 0, stream>>>(
        d_sw, dw, dsu, dsv, nullptr, nullptr, nullptr, out, 4096);
}